// Round 2
// baseline (184.157 us; speedup 1.0000x reference)
//
#include <hip/hip_runtime.h>
#include <math.h>

// Canny fused, round 2. Shapes fixed: B=16, C=3, H=W=512.
//
// Per 32x32 output tile (256 threads):
//   A: vertical 5-tap gauss DIRECTLY from global (zero-pad) -> vb[3][36][40]
//   B: horizontal 5-tap gauss vb -> bl[3][36][37]
//   C: Sobel/8 (edge-replicate clamp) + channel argmax (first-max) ->
//      mag[34][35] (overlaid on vb; 0 outside image = zero-pad of neigh conv)
//      + direction bucket dirm[32][32]
//   D: directional NMS (m >= both neighbors), threshold, sigmoid, store.
// 3 barriers total. Interior blocks (77%) take a checks-free template path.

#define TILE 32
#define HDIM 512
#define WDIM 512
#define VBW 40   // vb cols  (TILE + 2*4)
#define VBH 36   // vb rows  (TILE + 2*2)
#define BLS 37   // bl row stride (36 + 1 pad, odd -> spreads banks)
#define MTS 35   // mag row stride (34 + 1)

template<bool EDGE>
__device__ __forceinline__ void pipeline(
    const float* __restrict__ x, float t, float* __restrict__ out,
    int tx0, int ty0, int b,
    float* __restrict__ vbuf, float* __restrict__ bl,
    unsigned char* __restrict__ dirm)
{
    const int tid = threadIdx.x;
    const float w0 = 0.05448868454964294f;
    const float w1 = 0.24420134200323332f;
    const float w2 = 0.4026199468942475f;

    // ---- A: vertical gaussian, global -> vb[3][36][40] ----
    // map: 240 active threads = 12 rows x 20 float2-cols, 3 passes
    {
        const int rr = tid / 20;
        const int c2 = tid - rr * 20;
        const int cc = 2 * c2;
        if (tid < 240) {
            const int gc = tx0 - 4 + cc;
            for (int c = 0; c < 3; ++c) {
                const float* xc = x + ((size_t)(b * 3 + c)) * (HDIM * WDIM);
                #pragma unroll
                for (int p = 0; p < 3; ++p) {
                    const int r  = rr + 12 * p;
                    const int gr = ty0 - 2 + r;
                    float o0, o1;
                    if (!EDGE) {
                        const float* base = xc + (size_t)gr * WDIM + gc;
                        float2 a0 = *(const float2*)(base - 2 * WDIM);
                        float2 a1 = *(const float2*)(base - WDIM);
                        float2 a2 = *(const float2*)(base);
                        float2 a3 = *(const float2*)(base + WDIM);
                        float2 a4 = *(const float2*)(base + 2 * WDIM);
                        o0 = w0 * (a0.x + a4.x) + w1 * (a1.x + a3.x) + w2 * a2.x;
                        o1 = w0 * (a0.y + a4.y) + w1 * (a1.y + a3.y) + w2 * a2.y;
                    } else {
                        o0 = 0.f; o1 = 0.f;
                        #pragma unroll
                        for (int k = 0; k < 5; ++k) {
                            const int xr = gr - 2 + k;
                            if (xr >= 0 && xr < HDIM) {
                                const float wk = (k == 0 || k == 4) ? w0
                                               : ((k == 1 || k == 3) ? w1 : w2);
                                if ((unsigned)gc < (unsigned)WDIM)
                                    o0 += wk * xc[(size_t)xr * WDIM + gc];
                                if ((unsigned)(gc + 1) < (unsigned)WDIM)
                                    o1 += wk * xc[(size_t)xr * WDIM + gc + 1];
                            }
                        }
                    }
                    // (c*36+r)*40 + cc : even float index -> 8B aligned
                    *(float2*)&vbuf[(c * VBH + r) * VBW + cc] = make_float2(o0, o1);
                }
            }
        }
    }
    __syncthreads();

    // ---- B: horizontal gaussian, vb -> bl[3][36][37-stride] ----
    // map: 216 active threads = 12 rows x 18 float2-cols, 3 passes
    {
        const int rr = tid / 18;
        const int c2 = tid - rr * 18;
        const int cc = 2 * c2;
        if (tid < 216) {
            for (int c = 0; c < 3; ++c) {
                #pragma unroll
                for (int p = 0; p < 3; ++p) {
                    const int r = rr + 12 * p;
                    const float* vrow = &vbuf[(c * VBH + r) * VBW + cc];
                    float u0 = vrow[0], u1 = vrow[1], u2 = vrow[2];
                    float u3 = vrow[3], u4 = vrow[4], u5 = vrow[5];
                    float* d = &bl[(c * VBH + r) * BLS + cc];
                    d[0] = w0 * (u0 + u4) + w1 * (u1 + u3) + w2 * u2;
                    d[1] = w0 * (u1 + u5) + w1 * (u2 + u4) + w2 * u3;
                }
            }
        }
    }
    __syncthreads();

    // ---- C: sobel + argmax + magnitude + direction ----
    {
        float* mag = vbuf;  // overlay: vb is dead
        const float T1c = 0.41421356237309503f;
        const float T3c = 2.414213562373095f;
        for (unsigned i = tid; i < 34u * 34u; i += 256u) {
            const int r  = i / 34u;
            const int cc = i - r * 34u;
            const int gr = ty0 - 1 + r;
            const int gc = tx0 - 1 + cc;
            float m = 0.f;
            const bool valid = EDGE ? (gr >= 0 && gr < HDIM && gc >= 0 && gc < WDIM)
                                    : true;
            if (valid) {
                int rm, rp, cm, cp;
                if (EDGE) {
                    rm = max(gr - 1, 0) - ty0 + 2;
                    rp = min(gr + 1, HDIM - 1) - ty0 + 2;
                    cm = max(gc - 1, 0) - tx0 + 2;
                    cp = min(gc + 1, WDIM - 1) - tx0 + 2;
                } else {
                    rm = r; rp = r + 2; cm = cc; cp = cc + 2;
                }
                const int r0 = r + 1, c0 = cc + 1;
                float bestm2 = -1.f, bgx = 0.f, bgy = 0.f;
                #pragma unroll
                for (int c = 0; c < 3; ++c) {
                    const float* B0 = &bl[(c * VBH + rm) * BLS];
                    const float* B1 = &bl[(c * VBH + r0) * BLS];
                    const float* B2 = &bl[(c * VBH + rp) * BLS];
                    float a00 = B0[cm], a01 = B0[c0], a02 = B0[cp];
                    float a10 = B1[cm],               a12 = B1[cp];
                    float a20 = B2[cm], a21 = B2[c0], a22 = B2[cp];
                    float gx = 0.125f * ((a02 - a00) + 2.f * (a12 - a10) + (a22 - a20));
                    float gy = 0.125f * ((a20 - a00) + 2.f * (a21 - a01) + (a22 - a02));
                    float m2 = gx * gx + gy * gy;
                    if (m2 > bestm2) { bestm2 = m2; bgx = gx; bgy = gy; }
                }
                m = sqrtf(bestm2 + 1e-9f);
                if ((unsigned)(r - 1) < 32u && (unsigned)(cc - 1) < 32u) {
                    const float gys = (bgy == 0.f) ? 1e-9f : bgy;
                    const float a = bgx / gys;   // clip(+-10) preserves buckets
                    int d;
                    if (a >= -T1c && a < T1c)      d = 0;  // above/below
                    else if (a >= T1c && a < T3c)  d = 1;  // TL/BR
                    else if (a >= T3c || a < -T3c) d = 2;  // left/right
                    else                           d = 3;  // TR/BL
                    dirm[(r - 1) * 32 + (cc - 1)] = (unsigned char)d;
                }
            }
            mag[r * MTS + cc] = m;
        }
    }
    __syncthreads();

    // ---- D: NMS + threshold + sigmoid + store ----
    {
        const float* mag = vbuf;
        const int cc = tid & 31, rbase = tid >> 5;
        #pragma unroll
        for (int p = 0; p < 4; ++p) {
            const int r   = rbase + 8 * p;
            const int idx = (r + 1) * MTS + cc + 1;
            const float m = mag[idx];
            const int d   = dirm[r * 32 + cc];
            const int doff = (d == 0) ? MTS
                           : (d == 1) ? (MTS + 1)
                           : (d == 2) ? 1 : (MTS - 1);
            const float n1 = mag[idx - doff];
            const float n2 = mag[idx + doff];
            const float s  = (m >= n1 && m >= n2) ? m : 0.f;
            const float v  = (s >= t) ? s : 1e-9f;
            out[((size_t)b * HDIM + (ty0 + r)) * WDIM + (tx0 + cc)] =
                1.f / (1.f + __expf(-v));
        }
    }
}

__global__ __launch_bounds__(256, 6) void canny_fused(
    const float* __restrict__ x, const int* __restrict__ lt,
    float* __restrict__ out)
{
    __shared__ float vbuf[3 * VBH * VBW];          // 17280 B (later: mag overlay)
    __shared__ float blb[3 * VBH * BLS];           // 15984 B
    __shared__ unsigned char dirm[TILE * TILE];    // 1024 B
    const int tx0 = blockIdx.x * TILE;
    const int ty0 = blockIdx.y * TILE;
    const int b   = blockIdx.z;
    const float t = (float)lt[0];
    const bool interior = (blockIdx.x >= 1 && blockIdx.x <= 14 &&
                           blockIdx.y >= 1 && blockIdx.y <= 14);
    if (interior) pipeline<false>(x, t, out, tx0, ty0, b, vbuf, blb, dirm);
    else          pipeline<true >(x, t, out, tx0, ty0, b, vbuf, blb, dirm);
}

extern "C" void kernel_launch(void* const* d_in, const int* in_sizes, int n_in,
                              void* d_out, int out_size, void* d_ws, size_t ws_size,
                              hipStream_t stream) {
    const float* x  = (const float*)d_in[0];
    const int*   lt = (const int*)d_in[1];
    float* out = (float*)d_out;
    dim3 grid(WDIM / TILE, HDIM / TILE, 16);
    canny_fused<<<grid, dim3(256), 0, stream>>>(x, lt, out);
}

// Round 3
// 116.787 us; speedup vs baseline: 1.5769x; 1.5769x over previous
//
#include <hip/hip_runtime.h>
#include <math.h>

// Canny, round 3: wave-rolling stencil. B=16, C=3, H=W=512 fixed.
//
// No LDS, no __syncthreads. Each wave (64 lanes) owns a 56-col output strip
// (lane = column, 4-lane halo each side) and streams SH=16 rows downward:
//   - vertical 5-tap gauss: rolling 5-row register window per channel,
//     one coalesced row load per channel per step (zero-pad via mask)
//   - horizontal 5-tap gauss + sobel horizontal combos: __shfl (ds_bpermute)
//   - per-channel |g|^2 argmax in registers (strict > = first-max)
//   - NMS on a rolling 3-row mag window + dir regs, sigmoid, store.
// Edge-replicate (sobel) via per-row/per-lane selects; zero-pad (gauss, NMS
// neighbors) via masked loads / mag masking.

#define HDIM 512
#define WDIM 512
#define SH   16                 // output rows per wave
#define NSTR (HDIM / SH)        // 32 strips
#define NGRP 10                 // ceil(512/56) column groups
#define GW   56                 // valid output cols per wave

__device__ __forceinline__ float shfl1(float v, int src) {
    return __shfl(v, src, 64);
}

__global__ __launch_bounds__(256) void canny_wave(
    const float* __restrict__ x, const int* __restrict__ lt,
    float* __restrict__ out)
{
    const int lane = threadIdx.x & 63;
    const int wid  = blockIdx.x * 4 + (threadIdx.x >> 6);
    const int b    = wid / (NGRP * NSTR);
    const int rem  = wid - b * (NGRP * NSTR);
    const int g    = rem / NSTR;
    const int s    = rem - g * NSTR;
    const int R0   = s * SH;
    const int col  = g * GW + lane - 4;
    const bool colok = (unsigned)col < (unsigned)WDIM;
    const float t  = (float)lt[0];

    const float w0 = 0.05448868454964294f;   // gauss5(sigma=1)/sum
    const float w1 = 0.24420134200323332f;
    const float w2 = 0.4026199468942475f;
    const float T1c = 0.41421356237309503f;  // tan(pi/8)
    const float T3c = 2.414213562373095f;    // tan(3pi/8)

    // masked row load (zero outside image -> conv zero-pad)
    auto ld = [&](const float* base, int ri) -> float {
        float v = 0.f;
        if (colok && (unsigned)ri < (unsigned)HDIM)
            v = base[(size_t)ri * WDIM + col];
        return v;
    };
    // horizontal 5-tap blur across lanes
    auto hb = [&](float v) -> float {
        float l2 = shfl1(v, lane - 2), l1 = shfl1(v, lane - 1);
        float r1 = shfl1(v, lane + 1), r2 = shfl1(v, lane + 2);
        return w0 * (l2 + r2) + w1 * (l1 + r1) + w2 * v;
    };

    // rolling state
    float xa[3], xbw[3], xcw[3], xdw[3];   // x rows m-1 .. m+2
    float blm[3], bl0[3];                  // blurred rows m-1, m
    float mg0 = 0.f, mg1 = 0.f, mg2 = 0.f; // mag rows m-3, m-2, m-1
    int   d1 = 0, d2 = 0;                  // dir rows m-2, m-1

    // ---- prologue: build bl rows R0-2, R0-1; x window rows R0-2..R0+1 ----
    #pragma unroll
    for (int c = 0; c < 3; ++c) {
        const float* base = x + ((size_t)(b * 3 + c)) * (HDIM * WDIM);
        float t0 = ld(base, R0 - 4), t1 = ld(base, R0 - 3), t2 = ld(base, R0 - 2);
        float t3 = ld(base, R0 - 1), t4 = ld(base, R0),     t5 = ld(base, R0 + 1);
        float vA = w0 * (t0 + t4) + w1 * (t1 + t3) + w2 * t2;  // vb row R0-2
        float vB = w0 * (t1 + t5) + w1 * (t2 + t4) + w2 * t3;  // vb row R0-1
        blm[c] = hb(vA);
        bl0[c] = hb(vB);
        xa[c] = t2; xbw[c] = t3; xcw[c] = t4; xdw[c] = t5;
    }

    // ---- main loop: step m computes mag[m], outputs row m-2 ----
    for (int m = R0 - 1; m <= R0 + SH + 1; ++m) {
        // 1. prefetch x row m+3 (coalesced 256B per channel)
        float xn[3];
        #pragma unroll
        for (int c = 0; c < 3; ++c) {
            const float* base = x + ((size_t)(b * 3 + c)) * (HDIM * WDIM);
            xn[c] = ld(base, m + 3);
        }

        // 2. NMS + sigmoid + store for row m-2 (independent of the loads)
        if (m >= R0 + 2) {
            const float mm  = mg1;
            const float m0l = shfl1(mg0, lane - 1), m0r = shfl1(mg0, lane + 1);
            const float m1l = shfl1(mg1, lane - 1), m1r = shfl1(mg1, lane + 1);
            const float m2l = shfl1(mg2, lane - 1), m2r = shfl1(mg2, lane + 1);
            const float n1 = (d1 == 0) ? mg0 : (d1 == 1) ? m0l
                           : (d1 == 2) ? m1l : m0r;
            const float n2 = (d1 == 0) ? mg2 : (d1 == 1) ? m2r
                           : (d1 == 2) ? m1r : m2l;
            const float sres = (mm >= n1 && mm >= n2) ? mm : 0.f;
            const float v = (sres >= t) ? sres : 1e-9f;
            const float o = 1.f / (1.f + __expf(-v));
            if (colok && lane >= 4 && lane < 60)
                out[((size_t)b * HDIM + (m - 2)) * WDIM + col] = o;
        }

        // 3. vblur -> hblur -> sobel(row m) -> channel argmax
        float best = -1.f, bgx = 0.f, bgy = 0.f;
        #pragma unroll
        for (int c = 0; c < 3; ++c) {
            float vb  = w0 * (xa[c] + xn[c]) + w1 * (xbw[c] + xdw[c])
                      + w2 * xcw[c];                 // vb row m+1
            float blp = hb(vb);                      // bl row m+1
            // row edge-replicate for sobel
            float bm = (m == 0)        ? bl0[c] : blm[c];
            float bp = (m == HDIM - 1) ? bl0[c] : blp;
            float tt = bm + 2.f * bl0[c] + bp;       // column sums
            float uu = bp - bm;
            float tl = shfl1(tt, lane - 1), tr = shfl1(tt, lane + 1);
            float ul = shfl1(uu, lane - 1), ur = shfl1(uu, lane + 1);
            // col edge-replicate
            tl = (col == 0) ? tt : tl;  tr = (col == WDIM - 1) ? tt : tr;
            ul = (col == 0) ? uu : ul;  ur = (col == WDIM - 1) ? uu : ur;
            const float gx = 0.125f * (tr - tl);
            const float gy = 0.125f * (ul + 2.f * uu + ur);
            const float m2v = gx * gx + gy * gy;
            if (m2v > best) { best = m2v; bgx = gx; bgy = gy; }
            // shift windows
            blm[c] = bl0[c]; bl0[c] = blp;
            xa[c] = xbw[c]; xbw[c] = xcw[c]; xcw[c] = xdw[c]; xdw[c] = xn[c];
        }
        float mag = sqrtf(best + 1e-9f);
        if (!colok || (unsigned)m >= (unsigned)HDIM) mag = 0.f;  // zero-pad
        const float gys = (bgy == 0.f) ? 1e-9f : bgy;
        const float a = bgx / gys;   // clip(+-10) preserves bucket membership
        const int dn = (a >= T3c || a < -T3c) ? 2
                     : (a >= T1c) ? 1
                     : (a >= -T1c) ? 0 : 3;
        mg0 = mg1; mg1 = mg2; mg2 = mag;
        d1 = d2; d2 = dn;
    }
}

extern "C" void kernel_launch(void* const* d_in, const int* in_sizes, int n_in,
                              void* d_out, int out_size, void* d_ws, size_t ws_size,
                              hipStream_t stream) {
    const float* x  = (const float*)d_in[0];
    const int*   lt = (const int*)d_in[1];
    float* out = (float*)d_out;
    // 16 batches x 10 col-groups x 32 strips = 5120 waves = 1280 blocks
    const int nblocks = (16 * NGRP * NSTR) / 4;
    canny_wave<<<nblocks, dim3(256), 0, stream>>>(x, lt, out);
}